// Round 1
// baseline (1802.727 us; speedup 1.0000x reference)
//
#include <hip/hip_runtime.h>
#include <hip/hip_bf16.h>

// Model: 6 layers of  relu( spmm(graph, x @ W + b) )  over x:[B,255,F], B=256.
// Per call: build CSR for the 4 graphs (nnz=2040 each), then 6x (GEMM -> SpMM+ReLU),
// ping-ponging two fp32 buffers in d_ws.

#define NN 255   // graph nodes

struct Graphs {
    const int*   rows[4];
    const int*   cols[4];
    const float* vals[4];
    int*   cnt[4];
    int*   fill[4];
    int*   rowptr[4];
    int*   csr_col[4];
    float* csr_val[4];
};

__global__ void zero_k(int* p, int n) {
    int i = blockIdx.x * blockDim.x + threadIdx.x;
    if (i < n) p[i] = 0;
}

__global__ void count_k(Graphs g, int nnz) {
    int gi = blockIdx.y;
    int e = blockIdx.x * blockDim.x + threadIdx.x;
    if (e < nnz) atomicAdd(&g.cnt[gi][g.rows[gi][e]], 1);
}

__global__ void scan_k(Graphs g) {
    int gi = threadIdx.x;
    if (gi < 4) {
        const int* c = g.cnt[gi];
        int* rp = g.rowptr[gi];
        int s = 0;
        for (int i = 0; i < NN; ++i) { rp[i] = s; s += c[i]; }
        rp[NN] = s;
    }
}

__global__ void fill_k(Graphs g, int nnz) {
    int gi = blockIdx.y;
    int e = blockIdx.x * blockDim.x + threadIdx.x;
    if (e < nnz) {
        int r = g.rows[gi][e];
        int p = g.rowptr[gi][r] + atomicAdd(&g.fill[gi][r], 1);
        g.csr_col[gi][p] = g.cols[gi][e];
        g.csr_val[gi][p] = g.vals[gi][e];
    }
}

// ---------- GEMM: Y[m,n] = sum_k X[m,k] * W[k,n] + b[n] ----------

// K == 2 special case (layer 0): one thread per output element.
__global__ __launch_bounds__(256) void gemm_k2(const float* __restrict__ X,
                                               const float* __restrict__ W,
                                               const float* __restrict__ bias,
                                               float* __restrict__ Y,
                                               int M, int N) {
    int idx = blockIdx.x * blockDim.x + threadIdx.x;
    if (idx >= M * N) return;
    int m = idx / N;
    int n = idx - m * N;
    float x0 = X[m * 2], x1 = X[m * 2 + 1];
    Y[idx] = fmaf(x0, W[n], fmaf(x1, W[N + n], bias[n]));
}

// N == 2 special case (layer 5): one wave per row, shuffle-reduce.
__global__ __launch_bounds__(256) void gemm_n2(const float* __restrict__ X,
                                               const float* __restrict__ W,
                                               const float* __restrict__ bias,
                                               float* __restrict__ Y,
                                               int M, int K) {
    int wave = (blockIdx.x * blockDim.x + threadIdx.x) >> 6;
    int lane = threadIdx.x & 63;
    if (wave >= M) return;
    const float* Xr = X + (size_t)wave * K;
    float a0 = 0.f, a1 = 0.f;
    for (int k = lane; k < K; k += 64) {
        float x = Xr[k];
        a0 = fmaf(x, W[2 * k], a0);
        a1 = fmaf(x, W[2 * k + 1], a1);
    }
    #pragma unroll
    for (int off = 32; off; off >>= 1) {
        a0 += __shfl_down(a0, off);
        a1 += __shfl_down(a1, off);
    }
    if (lane == 0) {
        Y[(size_t)wave * 2]     = a0 + bias[0];
        Y[(size_t)wave * 2 + 1] = a1 + bias[1];
    }
}

// General tiled fp32 GEMM: 64x64 tile / block, 256 threads, 4x4 per thread, BK=16.
#define BM 64
#define BN 64
#define BK 16
__global__ __launch_bounds__(256) void gemm_bias_k(const float* __restrict__ A,
                                                   const float* __restrict__ W,
                                                   const float* __restrict__ bias,
                                                   float* __restrict__ C,
                                                   int M, int K, int N) {
    __shared__ float As[BM][BK + 1];
    __shared__ float Bs[BK][BN];
    int tid = threadIdx.x;
    int tx = tid & 15;   // col group (n)
    int ty = tid >> 4;   // row group (m)
    int m0 = blockIdx.x * BM;
    int n0 = blockIdx.y * BN;
    float acc[4][4] = {};

    for (int k0 = 0; k0 < K; k0 += BK) {
        // A tile: 64 rows x 16 k
        #pragma unroll
        for (int i = 0; i < 4; ++i) {
            int m = (tid >> 4) + i * 16;
            int k = tid & 15;
            int gm = m0 + m, gk = k0 + k;
            float v = 0.f;
            if (gm < M && gk < K) v = A[(size_t)gm * K + gk];
            As[m][k] = v;
        }
        // B tile: 16 k x 64 n
        #pragma unroll
        for (int i = 0; i < 4; ++i) {
            int k = (tid >> 6) + i * 4;
            int n = tid & 63;
            int gk = k0 + k, gn = n0 + n;
            float v = 0.f;
            if (gk < K && gn < N) v = W[(size_t)gk * N + gn];
            Bs[k][n] = v;
        }
        __syncthreads();
        #pragma unroll
        for (int kk = 0; kk < BK; ++kk) {
            float a[4], b[4];
            #pragma unroll
            for (int i = 0; i < 4; ++i) a[i] = As[ty * 4 + i][kk];
            #pragma unroll
            for (int j = 0; j < 4; ++j) b[j] = Bs[kk][tx * 4 + j];
            #pragma unroll
            for (int i = 0; i < 4; ++i)
                #pragma unroll
                for (int j = 0; j < 4; ++j)
                    acc[i][j] = fmaf(a[i], b[j], acc[i][j]);
        }
        __syncthreads();
    }

    #pragma unroll
    for (int i = 0; i < 4; ++i) {
        int gm = m0 + ty * 4 + i;
        if (gm >= M) continue;
        #pragma unroll
        for (int j = 0; j < 4; ++j) {
            int gn = n0 + tx * 4 + j;
            if (gn < N) C[(size_t)gm * N + gn] = acc[i][j] + bias[gn];
        }
    }
}

// ---------- SpMM + ReLU: Z[b,r,f] = relu( sum_e val[e] * Y[b,col[e],f] ) ----------

__global__ __launch_bounds__(128) void spmm_relu_k(const float* __restrict__ Y,
                                                   float* __restrict__ Z,
                                                   const int* __restrict__ rowptr,
                                                   const int* __restrict__ cols,
                                                   const float* __restrict__ vals,
                                                   int F) {
    int r = blockIdx.x;   // 0..254
    int b = blockIdx.y;
    int s = rowptr[r], e = rowptr[r + 1];
    const float* Yb = Y + (size_t)b * NN * F;
    float* Zr = Z + ((size_t)b * NN + r) * F;
    for (int f = threadIdx.x; f < F; f += blockDim.x) {
        float acc = 0.f;
        for (int i = s; i < e; ++i)
            acc = fmaf(vals[i], Yb[cols[i] * F + f], acc);
        Zr[f] = fmaxf(acc, 0.f);
    }
}

// F == 2 final layer, writes straight to d_out.
__global__ __launch_bounds__(256) void spmm_final_k(const float* __restrict__ Y,
                                                    float* __restrict__ Z,
                                                    const int* __restrict__ rowptr,
                                                    const int* __restrict__ cols,
                                                    const float* __restrict__ vals,
                                                    int total) {   // total = B*NN
    int t = blockIdx.x * blockDim.x + threadIdx.x;
    if (t >= total) return;
    int r = t % NN;
    int b = t / NN;
    int s = rowptr[r], e = rowptr[r + 1];
    const float* Yb = Y + (size_t)b * NN * 2;
    float a0 = 0.f, a1 = 0.f;
    for (int i = s; i < e; ++i) {
        float v = vals[i];
        int c = cols[i];
        a0 = fmaf(v, Yb[c * 2], a0);
        a1 = fmaf(v, Yb[c * 2 + 1], a1);
    }
    Z[(size_t)t * 2]     = fmaxf(a0, 0.f);
    Z[(size_t)t * 2 + 1] = fmaxf(a1, 0.f);
}

extern "C" void kernel_launch(void* const* d_in, const int* in_sizes, int n_in,
                              void* d_out, int out_size, void* d_ws, size_t ws_size,
                              hipStream_t stream) {
    const float* H = (const float*)d_in[0];
    // graphs: 0=sm_s, 1=sm_t, 2=sp_s, 3=sp_t
    const int*   g_rows[4] = {(const int*)d_in[1], (const int*)d_in[4], (const int*)d_in[7], (const int*)d_in[10]};
    const int*   g_cols[4] = {(const int*)d_in[2], (const int*)d_in[5], (const int*)d_in[8], (const int*)d_in[11]};
    const float* g_vals[4] = {(const float*)d_in[3], (const float*)d_in[6], (const float*)d_in[9], (const float*)d_in[12]};
    const float* W0  = (const float*)d_in[13]; const float* b0  = (const float*)d_in[14];
    const float* W1  = (const float*)d_in[15]; const float* b1  = (const float*)d_in[16];
    const float* W2  = (const float*)d_in[17]; const float* b2  = (const float*)d_in[18];
    const float* Wd0 = (const float*)d_in[19]; const float* bd0 = (const float*)d_in[20];
    const float* Wd1 = (const float*)d_in[21]; const float* bd1 = (const float*)d_in[22];
    const float* Wd2 = (const float*)d_in[23]; const float* bd2 = (const float*)d_in[24];
    float* out = (float*)d_out;

    const int nnz = in_sizes[1];
    const int B   = in_sizes[0] / (NN * 2);   // 256
    const int M   = B * NN;                   // 65280

    // workspace layout
    float* bufA = (float*)d_ws;                       // M*400 fp32
    float* bufB = bufA + (size_t)M * 400;             // M*400 fp32
    int*   cnt  = (int*)(bufB + (size_t)M * 400);     // 4*256
    int*   fil  = cnt + 4 * 256;                      // 4*256
    int*   rowp = fil + 4 * 256;                      // 4*256
    const int nnzp = (nnz + 63) & ~63;
    int*   ccol = rowp + 4 * 256;                     // 4*nnzp
    float* cval = (float*)(ccol + 4 * nnzp);          // 4*nnzp

    Graphs G;
    for (int i = 0; i < 4; ++i) {
        G.rows[i] = g_rows[i]; G.cols[i] = g_cols[i]; G.vals[i] = g_vals[i];
        G.cnt[i] = cnt + i * 256; G.fill[i] = fil + i * 256; G.rowptr[i] = rowp + i * 256;
        G.csr_col[i] = ccol + i * nnzp; G.csr_val[i] = cval + i * nnzp;
    }

    // CSR build (cheap: nnz=2040 x 4 graphs)
    zero_k<<<(2 * 4 * 256 + 255) / 256, 256, 0, stream>>>(cnt, 2 * 4 * 256);
    count_k<<<dim3((nnz + 255) / 256, 4), 256, 0, stream>>>(G, nnz);
    scan_k<<<1, 64, 0, stream>>>(G);
    fill_k<<<dim3((nnz + 255) / 256, 4), 256, 0, stream>>>(G, nnz);

    const int mb = M / 64;   // 1020 (M divisible by 64)

    // L0: [2->400], graph sm_s(0).   H -> bufB -> bufA
    gemm_k2<<<(M * 400 + 255) / 256, 256, 0, stream>>>(H, W0, b0, bufB, M, 400);
    spmm_relu_k<<<dim3(NN, B), 128, 0, stream>>>(bufB, bufA, G.rowptr[0], G.csr_col[0], G.csr_val[0], 400);

    // L1: [400->300], graph sm_s(0). bufA -> bufB -> bufA
    gemm_bias_k<<<dim3(mb, (300 + 63) / 64), 256, 0, stream>>>(bufA, W1, b1, bufB, M, 400, 300);
    spmm_relu_k<<<dim3(NN, B), 128, 0, stream>>>(bufB, bufA, G.rowptr[0], G.csr_col[0], G.csr_val[0], 300);

    // L2: [300->100], graph sm_t(1).
    gemm_bias_k<<<dim3(mb, (100 + 63) / 64), 256, 0, stream>>>(bufA, W2, b2, bufB, M, 300, 100);
    spmm_relu_k<<<dim3(NN, B), 128, 0, stream>>>(bufB, bufA, G.rowptr[1], G.csr_col[1], G.csr_val[1], 100);

    // L3: [100->300], graph sp_t(3).
    gemm_bias_k<<<dim3(mb, (300 + 63) / 64), 256, 0, stream>>>(bufA, Wd0, bd0, bufB, M, 100, 300);
    spmm_relu_k<<<dim3(NN, B), 128, 0, stream>>>(bufB, bufA, G.rowptr[3], G.csr_col[3], G.csr_val[3], 300);

    // L4: [300->400], graph sp_s(2).
    gemm_bias_k<<<dim3(mb, (400 + 63) / 64), 256, 0, stream>>>(bufA, Wd1, bd1, bufB, M, 300, 400);
    spmm_relu_k<<<dim3(NN, B), 128, 0, stream>>>(bufB, bufA, G.rowptr[2], G.csr_col[2], G.csr_val[2], 400);

    // L5: [400->2], graph sp_s(2).  bufA -> bufB -> d_out
    gemm_n2<<<(M * 64 + 255) / 256, 256, 0, stream>>>(bufA, Wd2, bd2, bufB, M, 400);
    spmm_final_k<<<(M + 255) / 256, 256, 0, stream>>>(bufB, out, G.rowptr[2], G.csr_col[2], G.csr_val[2], M);
}

// Round 2
// 795.336 us; speedup vs baseline: 2.2666x; 2.2666x over previous
//
#include <hip/hip_runtime.h>
#include <hip/hip_bf16.h>

// 6 layers of relu(spmm(graph, x@W+b)), B=256, N=255 nodes.
// R1: bf16 activation pipeline + MFMA 16x16x32_bf16 GEMMs (128x128 tiles).
// Weights pre-transposed/padded to [Npad, Kpad] bf16; activations stored
// [M, Kpad] bf16 zero-padded so the GEMM K-loop is branch-free.

#define NN 255

typedef __attribute__((ext_vector_type(8))) short short8;
typedef __attribute__((ext_vector_type(4))) short short4v;
typedef __attribute__((ext_vector_type(4))) float floatx4;

__device__ __forceinline__ float bf2f(ushort u) {
    union { uint u; float f; } c; c.u = ((uint)u) << 16; return c.f;
}
__device__ __forceinline__ ushort f2bf(float f) {
    union { float f; uint u; } c; c.f = f;
    uint u = c.u + 0x7fff + ((c.u >> 16) & 1);   // round-to-nearest-even
    return (ushort)(u >> 16);
}

// ---------------- CSR build ----------------
struct Graphs {
    const int*   rows[4];
    const int*   cols[4];
    const float* vals[4];
    int*   cnt[4];
    int*   fill[4];
    int*   rowptr[4];
    int*   csr_col[4];
    float* csr_val[4];
};

__global__ void zero_k(int* p, int n) {
    int i = blockIdx.x * blockDim.x + threadIdx.x;
    if (i < n) p[i] = 0;
}

__global__ void count_k(Graphs g, int nnz) {
    int gi = blockIdx.y;
    int e = blockIdx.x * blockDim.x + threadIdx.x;
    if (e < nnz) atomicAdd(&g.cnt[gi][g.rows[gi][e]], 1);
}

__global__ void scan_k(Graphs g) {
    int gi = threadIdx.x;
    if (gi < 4) {
        const int* c = g.cnt[gi];
        int* rp = g.rowptr[gi];
        int s = 0;
        for (int i = 0; i < NN; ++i) { rp[i] = s; s += c[i]; }
        rp[NN] = s;
    }
}

__global__ void fill_k(Graphs g, int nnz) {
    int gi = blockIdx.y;
    int e = blockIdx.x * blockDim.x + threadIdx.x;
    if (e < nnz) {
        int r = g.rows[gi][e];
        int p = g.rowptr[gi][r] + atomicAdd(&g.fill[gi][r], 1);
        g.csr_col[gi][p] = g.cols[gi][e];
        g.csr_val[gi][p] = g.vals[gi][e];
    }
}

// ---------------- weight convert: W[K,N] f32 -> Wt[Npad,Kpad] bf16 (transposed, zero-pad) ----
__global__ void wconv_k(const float* __restrict__ W, ushort* __restrict__ Wt,
                        int K, int N, int Kpad, int Npad) {
    int idx = blockIdx.x * blockDim.x + threadIdx.x;
    if (idx >= Npad * Kpad) return;
    int n = idx / Kpad, k = idx - n * Kpad;
    float v = (n < N && k < K) ? W[(size_t)k * N + n] : 0.f;
    Wt[idx] = f2bf(v);
}

// ---------------- layer-0 GEMM (K=2), bf16 out, 2 cols/thread ----------------
__global__ __launch_bounds__(256) void gemm_k2_bf16(const float* __restrict__ X,
                                                    const float* __restrict__ W,
                                                    const float* __restrict__ bias,
                                                    ushort* __restrict__ Y,
                                                    int M, int N) {
    int half = N >> 1;
    int idx = blockIdx.x * blockDim.x + threadIdx.x;
    if (idx >= M * half) return;
    int m = idx / half, n2 = (idx - m * half) * 2;
    float x0 = X[m * 2], x1 = X[m * 2 + 1];
    float y0 = fmaf(x0, W[n2],     fmaf(x1, W[N + n2],     bias[n2]));
    float y1 = fmaf(x0, W[n2 + 1], fmaf(x1, W[N + n2 + 1], bias[n2 + 1]));
    ((uint*)Y)[idx] = (uint)f2bf(y0) | ((uint)f2bf(y1) << 16);
}

// ---------------- MFMA GEMM: Y[M,N] = bf16( X[M,Kpad] @ Wt^T + b ) ----------------
// 128x128 block tile, 256 threads = 4 waves (2x2 of 64x64), BK=32.
// LDS row stride 36 bf16 (72 B): frag b64 reads land 4 dwords/bank (conflict-free).
#define LSTR 36

__device__ __forceinline__ short8 ld_frag(const ushort* p) {
    union { short8 v; short4v h[2]; } u;
    u.h[0] = *(const short4v*)p;
    u.h[1] = *(const short4v*)(p + 4);
    return u.v;
}

__global__ __launch_bounds__(256) void gemm_mfma(const ushort* __restrict__ X,
                                                 const ushort* __restrict__ Wt,
                                                 const float* __restrict__ bias,
                                                 ushort* __restrict__ Y,
                                                 int Kpad, int N) {
    __shared__ ushort As[128 * LSTR];
    __shared__ ushort Bs[128 * LSTR];
    int t = threadIdx.x;
    int m0 = blockIdx.x * 128, n0 = blockIdx.y * 128;

    // staging: thread t loads 16 bf16 of row (t>>1), k-half (t&1)
    int srow = t >> 1, scol = (t & 1) * 16;
    const uint4* Ag = (const uint4*)(X  + (size_t)(m0 + srow) * Kpad + scol);
    const uint4* Bg = (const uint4*)(Wt + (size_t)(n0 + srow) * Kpad + scol);
    uint2* Aw = (uint2*)&As[srow * LSTR + scol];
    uint2* Bw = (uint2*)&Bs[srow * LSTR + scol];

    int wave = t >> 6, lane = t & 63;
    int wm = (wave >> 1) * 64, wn = (wave & 1) * 64;
    int frow = lane & 15, quad = lane >> 4, fq = quad * 8;
    const ushort* Ab = &As[(wm + frow) * LSTR + fq];
    const ushort* Bb = &Bs[(wn + frow) * LSTR + fq];

    floatx4 acc[4][4];
    #pragma unroll
    for (int i = 0; i < 4; ++i)
        #pragma unroll
        for (int j = 0; j < 4; ++j) acc[i][j] = (floatx4)0.f;

    int nk = Kpad >> 5;
    uint4 a0 = Ag[0], a1 = Ag[1];
    uint4 b0 = Bg[0], b1 = Bg[1];
    Ag += 4; Bg += 4;

    for (int ks = 0; ks < nk; ++ks) {
        __syncthreads();
        Aw[0] = make_uint2(a0.x, a0.y); Aw[1] = make_uint2(a0.z, a0.w);
        Aw[2] = make_uint2(a1.x, a1.y); Aw[3] = make_uint2(a1.z, a1.w);
        Bw[0] = make_uint2(b0.x, b0.y); Bw[1] = make_uint2(b0.z, b0.w);
        Bw[2] = make_uint2(b1.x, b1.y); Bw[3] = make_uint2(b1.z, b1.w);
        __syncthreads();
        if (ks + 1 < nk) {   // prefetch next tile into regs, retires during MFMAs
            a0 = Ag[0]; a1 = Ag[1]; b0 = Bg[0]; b1 = Bg[1];
            Ag += 4; Bg += 4;
        }
        short8 af[4], bf[4];
        #pragma unroll
        for (int i = 0; i < 4; ++i) {
            af[i] = ld_frag(Ab + i * 16 * LSTR);
            bf[i] = ld_frag(Bb + i * 16 * LSTR);
        }
        #pragma unroll
        for (int i = 0; i < 4; ++i)
            #pragma unroll
            for (int j = 0; j < 4; ++j)
                acc[i][j] = __builtin_amdgcn_mfma_f32_16x16x32_bf16(af[i], bf[j], acc[i][j], 0, 0, 0);
    }

    // epilogue: C/D layout col=lane&15, row=quad*4+reg (m89-verified)
    #pragma unroll
    for (int j = 0; j < 4; ++j) {
        int gn = n0 + wn + j * 16 + frow;
        if (gn >= N) continue;
        float bv = bias[gn];
        #pragma unroll
        for (int i = 0; i < 4; ++i) {
            int gm = m0 + wm + i * 16 + quad * 4;
            #pragma unroll
            for (int r = 0; r < 4; ++r)
                Y[(size_t)(gm + r) * N + gn] = f2bf(acc[i][j][r] + bv);
        }
    }
}

// ---------------- SpMM + ReLU, bf16 in/out, 2 feats/thread, zero-pads to Fpad ----
__global__ __launch_bounds__(128) void spmm_relu_bf16(const ushort* __restrict__ Yv,
                                                      ushort* __restrict__ Z,
                                                      const int* __restrict__ rowptr,
                                                      const int* __restrict__ cols,
                                                      const float* __restrict__ vals,
                                                      int F, int Fpad) {
    int r = blockIdx.x, b = blockIdx.y;
    int s = rowptr[r], e = rowptr[r + 1];
    const ushort* Yb = Yv + (size_t)b * NN * F;
    uint* Zr = (uint*)(Z + ((size_t)b * NN + r) * Fpad);
    int F2 = F >> 1, Fp2 = Fpad >> 1;
    for (int f = threadIdx.x; f < Fp2; f += 128) {
        uint o = 0;
        if (f < F2) {
            float a0 = 0.f, a1 = 0.f;
            for (int i = s; i < e; ++i) {
                float v = vals[i];
                uint p = ((const uint*)(Yb + cols[i] * F))[f];
                a0 = fmaf(v, bf2f((ushort)(p & 0xffffu)), a0);
                a1 = fmaf(v, bf2f((ushort)(p >> 16)), a1);
            }
            o = (uint)f2bf(fmaxf(a0, 0.f)) | ((uint)f2bf(fmaxf(a1, 0.f)) << 16);
        }
        Zr[f] = o;
    }
}

// ---------------- layer-5 GEMM (N=2): wave/row, bf16 in, f32 out ----------------
__global__ __launch_bounds__(256) void gemm_n2_bf16(const ushort* __restrict__ X,
                                                    const float* __restrict__ W,
                                                    const float* __restrict__ bias,
                                                    float* __restrict__ Y,
                                                    int M, int K) {
    int wv = (blockIdx.x * blockDim.x + threadIdx.x) >> 6;
    int lane = threadIdx.x & 63;
    if (wv >= M) return;
    const uint* Xr = (const uint*)(X + (size_t)wv * K);
    int K2 = K >> 1;
    float a0 = 0.f, a1 = 0.f;
    for (int k2 = lane; k2 < K2; k2 += 64) {
        uint p = Xr[k2];
        float x0 = bf2f((ushort)(p & 0xffffu)), x1 = bf2f((ushort)(p >> 16));
        float4 w = ((const float4*)W)[k2];   // {W[k][0],W[k][1],W[k+1][0],W[k+1][1]}
        a0 = fmaf(x0, w.x, fmaf(x1, w.z, a0));
        a1 = fmaf(x0, w.y, fmaf(x1, w.w, a1));
    }
    #pragma unroll
    for (int off = 32; off; off >>= 1) {
        a0 += __shfl_down(a0, off);
        a1 += __shfl_down(a1, off);
    }
    if (lane == 0) {
        Y[(size_t)wv * 2]     = a0 + bias[0];
        Y[(size_t)wv * 2 + 1] = a1 + bias[1];
    }
}

// ---------------- final SpMM (F=2), f32 in, f32 out ----------------
__global__ __launch_bounds__(256) void spmm_final_k(const float* __restrict__ Y,
                                                    float* __restrict__ Z,
                                                    const int* __restrict__ rowptr,
                                                    const int* __restrict__ cols,
                                                    const float* __restrict__ vals,
                                                    int total) {
    int tt = blockIdx.x * blockDim.x + threadIdx.x;
    if (tt >= total) return;
    int r = tt % NN;
    int b = tt / NN;
    int s = rowptr[r], e = rowptr[r + 1];
    const float* Yb = Y + (size_t)b * NN * 2;
    float a0 = 0.f, a1 = 0.f;
    for (int i = s; i < e; ++i) {
        float v = vals[i];
        int c = cols[i];
        a0 = fmaf(v, Yb[c * 2], a0);
        a1 = fmaf(v, Yb[c * 2 + 1], a1);
    }
    Z[(size_t)tt * 2]     = fmaxf(a0, 0.f);
    Z[(size_t)tt * 2 + 1] = fmaxf(a1, 0.f);
}

extern "C" void kernel_launch(void* const* d_in, const int* in_sizes, int n_in,
                              void* d_out, int out_size, void* d_ws, size_t ws_size,
                              hipStream_t stream) {
    const float* H = (const float*)d_in[0];
    const int*   g_rows[4] = {(const int*)d_in[1], (const int*)d_in[4], (const int*)d_in[7], (const int*)d_in[10]};
    const int*   g_cols[4] = {(const int*)d_in[2], (const int*)d_in[5], (const int*)d_in[8], (const int*)d_in[11]};
    const float* g_vals[4] = {(const float*)d_in[3], (const float*)d_in[6], (const float*)d_in[9], (const float*)d_in[12]};
    const float* W0  = (const float*)d_in[13]; const float* b0  = (const float*)d_in[14];
    const float* W1  = (const float*)d_in[15]; const float* b1  = (const float*)d_in[16];
    const float* W2  = (const float*)d_in[17]; const float* b2  = (const float*)d_in[18];
    const float* Wd0 = (const float*)d_in[19]; const float* bd0 = (const float*)d_in[20];
    const float* Wd1 = (const float*)d_in[21]; const float* bd1 = (const float*)d_in[22];
    const float* Wd2 = (const float*)d_in[23]; const float* bd2 = (const float*)d_in[24];
    float* out = (float*)d_out;

    const int nnz = in_sizes[1];
    const int B   = in_sizes[0] / (NN * 2);   // 256
    const int M   = B * NN;                   // 65280 = 510*128

    // ---- workspace layout (16B-aligned chunks) ----
    ushort* bufS = (ushort*)d_ws;                    // activations X  [M,416] bf16
    ushort* bufG = bufS + (size_t)M * 416;           // gemm out    Y  [M,416] bf16
    ushort* Wt1 = bufG + (size_t)M * 416;            // [384,416]
    ushort* Wt2 = Wt1 + 384 * 416;                   // [128,320]
    ushort* Wt3 = Wt2 + 128 * 320;                   // [384,128]
    ushort* Wt4 = Wt3 + 384 * 128;                   // [512,320]
    int*    cnt = (int*)(Wt4 + 512 * 320);
    int*    fil = cnt + 4 * 256;
    int*    rowp = fil + 4 * 256;
    const int nnzp = (nnz + 63) & ~63;
    int*    ccol = rowp + 4 * 256;
    float*  cval = (float*)(ccol + 4 * nnzp);

    Graphs G;
    for (int i = 0; i < 4; ++i) {
        G.rows[i] = g_rows[i]; G.cols[i] = g_cols[i]; G.vals[i] = g_vals[i];
        G.cnt[i] = cnt + i * 256; G.fill[i] = fil + i * 256; G.rowptr[i] = rowp + i * 256;
        G.csr_col[i] = ccol + i * nnzp; G.csr_val[i] = cval + i * nnzp;
    }

    // CSR build
    zero_k<<<(2 * 4 * 256 + 255) / 256, 256, 0, stream>>>(cnt, 2 * 4 * 256);
    count_k<<<dim3((nnz + 255) / 256, 4), 256, 0, stream>>>(G, nnz);
    scan_k<<<1, 64, 0, stream>>>(G);
    fill_k<<<dim3((nnz + 255) / 256, 4), 256, 0, stream>>>(G, nnz);

    // weight transpose+convert (tiny)
    wconv_k<<<(384 * 416 + 255) / 256, 256, 0, stream>>>(W1, Wt1, 400, 300, 416, 384);
    wconv_k<<<(128 * 320 + 255) / 256, 256, 0, stream>>>(W2, Wt2, 300, 100, 320, 128);
    wconv_k<<<(384 * 128 + 255) / 256, 256, 0, stream>>>(Wd0, Wt3, 100, 300, 128, 384);
    wconv_k<<<(512 * 320 + 255) / 256, 256, 0, stream>>>(Wd1, Wt4, 300, 400, 320, 512);

    const int mt = M / 128;  // 510

    // L0: [2->400] g0.  H -> bufG[,400] -> bufS[,416]
    gemm_k2_bf16<<<(M * 200 + 255) / 256, 256, 0, stream>>>(H, W0, b0, bufG, M, 400);
    spmm_relu_bf16<<<dim3(NN, B), 128, 0, stream>>>(bufG, bufS, G.rowptr[0], G.csr_col[0], G.csr_val[0], 400, 416);

    // L1: [400->300] g0.  bufS(K416) -> bufG[,300] -> bufS[,320]
    gemm_mfma<<<dim3(mt, 3), 256, 0, stream>>>(bufS, Wt1, b1, bufG, 416, 300);
    spmm_relu_bf16<<<dim3(NN, B), 128, 0, stream>>>(bufG, bufS, G.rowptr[0], G.csr_col[0], G.csr_val[0], 300, 320);

    // L2: [300->100] g1.  bufS(K320) -> bufG[,100] -> bufS[,128]
    gemm_mfma<<<dim3(mt, 1), 256, 0, stream>>>(bufS, Wt2, b2, bufG, 320, 100);
    spmm_relu_bf16<<<dim3(NN, B), 128, 0, stream>>>(bufG, bufS, G.rowptr[1], G.csr_col[1], G.csr_val[1], 100, 128);

    // L3: [100->300] g3.  bufS(K128) -> bufG[,300] -> bufS[,320]
    gemm_mfma<<<dim3(mt, 3), 256, 0, stream>>>(bufS, Wt3, bd0, bufG, 128, 300);
    spmm_relu_bf16<<<dim3(NN, B), 128, 0, stream>>>(bufG, bufS, G.rowptr[3], G.csr_col[3], G.csr_val[3], 300, 320);

    // L4: [300->400] g2.  bufS(K320) -> bufG[,400] -> bufS[,400] (no pad; L5 loops K=400 exactly)
    gemm_mfma<<<dim3(mt, 4), 256, 0, stream>>>(bufS, Wt4, bd1, bufG, 320, 400);
    spmm_relu_bf16<<<dim3(NN, B), 128, 0, stream>>>(bufG, bufS, G.rowptr[2], G.csr_col[2], G.csr_val[2], 400, 400);

    // L5: [400->2] g2.  bufS -> (float*)bufG[M,2] -> out
    gemm_n2_bf16<<<(M * 64 + 255) / 256, 256, 0, stream>>>(bufS, Wd2, bd2, (float*)bufG, M, 400);
    spmm_final_k<<<(M + 255) / 256, 256, 0, stream>>>((float*)bufG, out, G.rowptr[2], G.csr_col[2], G.csr_val[2], M);
}

// Round 3
// 623.417 us; speedup vs baseline: 2.8917x; 1.2758x over previous
//
#include <hip/hip_runtime.h>
#include <hip/hip_bf16.h>

// 6 layers of relu(spmm(graph, x@W+b)), B=256, NN=255 nodes, M=B*NN=65280.
// R2: commute spmm with GEMM per-layer (spmm is linear; bias becomes rowsum[r]*b[n],
// relu folds into GEMM epilogue), XCD-swizzled spmm for L2 locality.

#define NN 255

typedef __attribute__((ext_vector_type(8))) short short8;
typedef __attribute__((ext_vector_type(4))) short short4v;
typedef __attribute__((ext_vector_type(4))) float floatx4;

__device__ __forceinline__ float bf2f(ushort u) {
    union { uint u; float f; } c; c.u = ((uint)u) << 16; return c.f;
}
__device__ __forceinline__ ushort f2bf(float f) {
    union { float f; uint u; } c; c.f = f;
    uint u = c.u + 0x7fff + ((c.u >> 16) & 1);
    return (ushort)(u >> 16);
}

// ---------------- CSR build ----------------
struct Graphs {
    const int*   rows[4];
    const int*   cols[4];
    const float* vals[4];
    int*   cnt[4];
    int*   fill[4];
    int*   rowptr[4];
    int*   csr_col[4];
    float* csr_val[4];
};

__global__ void zero_k(int* p, int n) {
    int i = blockIdx.x * blockDim.x + threadIdx.x;
    if (i < n) p[i] = 0;
}

__global__ void count_k(Graphs g, int nnz) {
    int gi = blockIdx.y;
    int e = blockIdx.x * blockDim.x + threadIdx.x;
    if (e < nnz) atomicAdd(&g.cnt[gi][g.rows[gi][e]], 1);
}

__global__ void scan_k(Graphs g) {
    int gi = threadIdx.x;
    if (gi < 4) {
        const int* c = g.cnt[gi];
        int* rp = g.rowptr[gi];
        int s = 0;
        for (int i = 0; i < NN; ++i) { rp[i] = s; s += c[i]; }
        rp[NN] = s;
    }
}

__global__ void fill_k(Graphs g, int nnz) {
    int gi = blockIdx.y;
    int e = blockIdx.x * blockDim.x + threadIdx.x;
    if (e < nnz) {
        int r = g.rows[gi][e];
        int p = g.rowptr[gi][r] + atomicAdd(&g.fill[gi][r], 1);
        g.csr_col[gi][p] = g.cols[gi][e];
        g.csr_val[gi][p] = g.vals[gi][e];
    }
}

// rowsum[gi][r] = sum of vals in row r (for commuted bias)
__global__ void rowsum_k(Graphs g, float* rs) {
    int gi = blockIdx.x, r = threadIdx.x;
    if (r < NN) {
        int s = g.rowptr[gi][r], e = g.rowptr[gi][r + 1];
        float a = 0.f;
        for (int i = s; i < e; ++i) a += g.csr_val[gi][i];
        rs[gi * 256 + r] = a;
    }
}

// ---- weight convert: W[K,N] f32 -> Wt[Npad,Kpad] bf16 (transposed, zero-pad) ----
__global__ void wconv_k(const float* __restrict__ W, ushort* __restrict__ Wt,
                        int K, int N, int Kpad, int Npad) {
    int idx = blockIdx.x * blockDim.x + threadIdx.x;
    if (idx >= Npad * Kpad) return;
    int n = idx / Kpad, k = idx - n * Kpad;
    float v = (n < N && k < K) ? W[(size_t)k * N + n] : 0.f;
    Wt[idx] = f2bf(v);
}

// ---------------- L0 spmm: F=2, f32 in (H), f32 out ----------------
__global__ __launch_bounds__(256) void spmm_f2_f32(const float* __restrict__ H,
                                                   float* __restrict__ T,
                                                   const int* __restrict__ rowptr,
                                                   const int* __restrict__ cols,
                                                   const float* __restrict__ vals,
                                                   int total) {
    int tt = blockIdx.x * blockDim.x + threadIdx.x;
    if (tt >= total) return;
    int r = tt % NN, b = tt / NN;
    int s = rowptr[r], e = rowptr[r + 1];
    const float* Hb = H + (size_t)b * NN * 2;
    float a0 = 0.f, a1 = 0.f;
    for (int i = s; i < e; ++i) {
        float v = vals[i]; int c = cols[i];
        a0 = fmaf(v, Hb[c * 2], a0);
        a1 = fmaf(v, Hb[c * 2 + 1], a1);
    }
    T[(size_t)tt * 2] = a0;
    T[(size_t)tt * 2 + 1] = a1;
}

// -------- L0 GEMM (K=2) with relu(acc + rs[r]*b[n]), bf16 out stride 416 --------
__global__ __launch_bounds__(256) void gemm_k2_relu(const float* __restrict__ T,
                                                    const float* __restrict__ W,
                                                    const float* __restrict__ bias,
                                                    const float* __restrict__ rs,
                                                    ushort* __restrict__ Y,
                                                    int M, int N, int Nstride) {
    int half = Nstride >> 1;                       // 208
    int idx = blockIdx.x * blockDim.x + threadIdx.x;
    if (idx >= M * half) return;
    int m = idx / half, n2 = (idx - m * half) * 2;
    uint o = 0;
    if (n2 < N) {
        float x0 = T[m * 2], x1 = T[m * 2 + 1];
        float rsm = rs[m % NN];
        float y0 = fmaf(x0, W[n2],     fmaf(x1, W[N + n2],     rsm * bias[n2]));
        float y1 = fmaf(x0, W[n2 + 1], fmaf(x1, W[N + n2 + 1], rsm * bias[n2 + 1]));
        y0 = fmaxf(y0, 0.f); y1 = fmaxf(y1, 0.f);
        o = (uint)f2bf(y0) | ((uint)f2bf(y1) << 16);
    }
    ((uint*)Y)[idx] = o;
}

// ---------------- MFMA GEMM: Y[M,Nstride] = X[M,Kpad] @ Wt^T (+bias terms) ----------------
// 128x128 tile, 256 thr = 4 waves (2x2 of 64x64), BK=32. LDS stride 36 (conflict-free).
// rs==nullptr: Y = acc + bias[n]          (no relu)
// rs!=nullptr: Y = relu(acc + rs[m%NN]*bias[n])
#define LSTR 36

__device__ __forceinline__ short8 ld_frag(const ushort* p) {
    union { short8 v; short4v h[2]; } u;
    u.h[0] = *(const short4v*)p;
    u.h[1] = *(const short4v*)(p + 4);
    return u.v;
}

__global__ __launch_bounds__(256) void gemm_mfma(const ushort* __restrict__ X,
                                                 const ushort* __restrict__ Wt,
                                                 const float* __restrict__ bias,
                                                 const float* __restrict__ rs,
                                                 ushort* __restrict__ Y,
                                                 int Kpad, int N, int Nstride) {
    __shared__ ushort As[128 * LSTR];
    __shared__ ushort Bs[128 * LSTR];
    int t = threadIdx.x;
    int m0 = blockIdx.x * 128, n0 = blockIdx.y * 128;

    int srow = t >> 1, scol = (t & 1) * 16;
    const uint4* Ag = (const uint4*)(X  + (size_t)(m0 + srow) * Kpad + scol);
    const uint4* Bg = (const uint4*)(Wt + (size_t)(n0 + srow) * Kpad + scol);
    uint2* Aw = (uint2*)&As[srow * LSTR + scol];
    uint2* Bw = (uint2*)&Bs[srow * LSTR + scol];

    int wave = t >> 6, lane = t & 63;
    int wm = (wave >> 1) * 64, wn = (wave & 1) * 64;
    int frow = lane & 15, quad = lane >> 4, fq = quad * 8;
    const ushort* Ab = &As[(wm + frow) * LSTR + fq];
    const ushort* Bb = &Bs[(wn + frow) * LSTR + fq];

    floatx4 acc[4][4];
    #pragma unroll
    for (int i = 0; i < 4; ++i)
        #pragma unroll
        for (int j = 0; j < 4; ++j) acc[i][j] = (floatx4)0.f;

    int nk = Kpad >> 5;
    uint4 a0 = Ag[0], a1 = Ag[1];
    uint4 b0 = Bg[0], b1 = Bg[1];
    Ag += 4; Bg += 4;

    for (int ks = 0; ks < nk; ++ks) {
        __syncthreads();
        Aw[0] = make_uint2(a0.x, a0.y); Aw[1] = make_uint2(a0.z, a0.w);
        Aw[2] = make_uint2(a1.x, a1.y); Aw[3] = make_uint2(a1.z, a1.w);
        Bw[0] = make_uint2(b0.x, b0.y); Bw[1] = make_uint2(b0.z, b0.w);
        Bw[2] = make_uint2(b1.x, b1.y); Bw[3] = make_uint2(b1.z, b1.w);
        __syncthreads();
        if (ks + 1 < nk) {
            a0 = Ag[0]; a1 = Ag[1]; b0 = Bg[0]; b1 = Bg[1];
            Ag += 4; Bg += 4;
        }
        short8 af[4], bf[4];
        #pragma unroll
        for (int i = 0; i < 4; ++i) {
            af[i] = ld_frag(Ab + i * 16 * LSTR);
            bf[i] = ld_frag(Bb + i * 16 * LSTR);
        }
        #pragma unroll
        for (int i = 0; i < 4; ++i)
            #pragma unroll
            for (int j = 0; j < 4; ++j)
                acc[i][j] = __builtin_amdgcn_mfma_f32_16x16x32_bf16(af[i], bf[j], acc[i][j], 0, 0, 0);
    }

    // C/D layout: col=lane&15, row=quad*4+reg
    #pragma unroll
    for (int j = 0; j < 4; ++j) {
        int gn = n0 + wn + j * 16 + frow;
        if (gn >= Nstride) continue;
        float bv = (gn < N) ? bias[gn] : 0.f;
        #pragma unroll
        for (int i = 0; i < 4; ++i) {
            int gm = m0 + wm + i * 16 + quad * 4;
            #pragma unroll
            for (int r = 0; r < 4; ++r) {
                float val;
                if (gn < N) {
                    if (rs) {
                        val = acc[i][j][r] + rs[(gm + r) % NN] * bv;
                        val = fmaxf(val, 0.f);
                    } else {
                        val = acc[i][j][r] + bv;
                    }
                } else val = 0.f;
                Y[(size_t)(gm + r) * Nstride + gn] = f2bf(val);
            }
        }
    }
}

// ------------- SpMM bf16, XCD-swizzled, optional relu, padded width Fp -------------
__global__ __launch_bounds__(128) void spmm_bf16(const ushort* __restrict__ Yv,
                                                 ushort* __restrict__ Z,
                                                 const int* __restrict__ rowptr,
                                                 const int* __restrict__ cols,
                                                 const float* __restrict__ vals,
                                                 int Fp, int relu) {
    int l = blockIdx.x;
    int xcd = l & 7, w = l >> 3;
    int bg = w / NN;
    int r = w - bg * NN;
    int b = xcd + (bg << 3);
    int s = rowptr[r], e = rowptr[r + 1];
    int F2 = Fp >> 1;
    const uint* Yb = (const uint*)Yv + (size_t)b * NN * F2;
    uint* Zr = (uint*)Z + ((size_t)b * NN + r) * F2;
    for (int f = threadIdx.x; f < F2; f += 128) {
        float a0 = 0.f, a1 = 0.f;
        for (int i = s; i < e; ++i) {
            float v = vals[i];
            uint p = Yb[cols[i] * F2 + f];
            a0 = fmaf(v, bf2f((ushort)(p & 0xffffu)), a0);
            a1 = fmaf(v, bf2f((ushort)(p >> 16)), a1);
        }
        if (relu) { a0 = fmaxf(a0, 0.f); a1 = fmaxf(a1, 0.f); }
        Zr[f] = (uint)f2bf(a0) | ((uint)f2bf(a1) << 16);
    }
}

// ---------------- L5 GEMM (N=2): wave/row, bf16 in, f32 out ----------------
__global__ __launch_bounds__(256) void gemm_n2_bf16(const ushort* __restrict__ X,
                                                    const float* __restrict__ W,
                                                    const float* __restrict__ bias,
                                                    float* __restrict__ Y,
                                                    int M, int K) {
    int wv = (blockIdx.x * blockDim.x + threadIdx.x) >> 6;
    int lane = threadIdx.x & 63;
    if (wv >= M) return;
    const uint* Xr = (const uint*)(X + (size_t)wv * K);
    int K2 = K >> 1;
    float a0 = 0.f, a1 = 0.f;
    for (int k2 = lane; k2 < K2; k2 += 64) {
        uint p = Xr[k2];
        float x0 = bf2f((ushort)(p & 0xffffu)), x1 = bf2f((ushort)(p >> 16));
        float4 w = ((const float4*)W)[k2];
        a0 = fmaf(x0, w.x, fmaf(x1, w.z, a0));
        a1 = fmaf(x0, w.y, fmaf(x1, w.w, a1));
    }
    #pragma unroll
    for (int off = 32; off; off >>= 1) {
        a0 += __shfl_down(a0, off);
        a1 += __shfl_down(a1, off);
    }
    if (lane == 0) {
        Y[(size_t)wv * 2]     = a0 + bias[0];
        Y[(size_t)wv * 2 + 1] = a1 + bias[1];
    }
}

// ---------------- final SpMM (F=2) + relu, f32 in, f32 out ----------------
__global__ __launch_bounds__(256) void spmm_final_k(const float* __restrict__ Y,
                                                    float* __restrict__ Z,
                                                    const int* __restrict__ rowptr,
                                                    const int* __restrict__ cols,
                                                    const float* __restrict__ vals,
                                                    int total) {
    int tt = blockIdx.x * blockDim.x + threadIdx.x;
    if (tt >= total) return;
    int r = tt % NN, b = tt / NN;
    int s = rowptr[r], e = rowptr[r + 1];
    const float* Yb = Y + (size_t)b * NN * 2;
    float a0 = 0.f, a1 = 0.f;
    for (int i = s; i < e; ++i) {
        float v = vals[i]; int c = cols[i];
        a0 = fmaf(v, Yb[c * 2], a0);
        a1 = fmaf(v, Yb[c * 2 + 1], a1);
    }
    Z[(size_t)tt * 2]     = fmaxf(a0, 0.f);
    Z[(size_t)tt * 2 + 1] = fmaxf(a1, 0.f);
}

extern "C" void kernel_launch(void* const* d_in, const int* in_sizes, int n_in,
                              void* d_out, int out_size, void* d_ws, size_t ws_size,
                              hipStream_t stream) {
    const float* H = (const float*)d_in[0];
    const int*   g_rows[4] = {(const int*)d_in[1], (const int*)d_in[4], (const int*)d_in[7], (const int*)d_in[10]};
    const int*   g_cols[4] = {(const int*)d_in[2], (const int*)d_in[5], (const int*)d_in[8], (const int*)d_in[11]};
    const float* g_vals[4] = {(const float*)d_in[3], (const float*)d_in[6], (const float*)d_in[9], (const float*)d_in[12]};
    const float* W0  = (const float*)d_in[13]; const float* b0  = (const float*)d_in[14];
    const float* W1  = (const float*)d_in[15]; const float* b1  = (const float*)d_in[16];
    const float* W2  = (const float*)d_in[17]; const float* b2  = (const float*)d_in[18];
    const float* Wd0 = (const float*)d_in[19]; const float* bd0 = (const float*)d_in[20];
    const float* Wd1 = (const float*)d_in[21]; const float* bd1 = (const float*)d_in[22];
    const float* Wd2 = (const float*)d_in[23]; const float* bd2 = (const float*)d_in[24];
    float* out = (float*)d_out;

    const int nnz = in_sizes[1];
    const int B   = in_sizes[0] / (NN * 2);   // 256
    const int M   = B * NN;                   // 65280 = 510*128

    // ---- workspace ----
    ushort* bufS = (ushort*)d_ws;                    // [M,416] bf16
    ushort* bufG = bufS + (size_t)M * 416;           // [M,416] bf16 (also f32 [M,2] temp)
    ushort* Wt1 = bufG + (size_t)M * 416;            // [384,416]
    ushort* Wt2 = Wt1 + 384 * 416;                   // [128,320]
    ushort* Wt3 = Wt2 + 128 * 320;                   // [384,128]
    ushort* Wt4 = Wt3 + 384 * 128;                   // [512,320]
    float*  rs  = (float*)(Wt4 + 512 * 320);         // [4][256]
    int*    cnt = (int*)(rs + 4 * 256);
    int*    fil = cnt + 4 * 256;
    int*    rowp = fil + 4 * 256;
    const int nnzp = (nnz + 63) & ~63;
    int*    ccol = rowp + 4 * 256;
    float*  cval = (float*)(ccol + 4 * nnzp);

    Graphs G;
    for (int i = 0; i < 4; ++i) {
        G.rows[i] = g_rows[i]; G.cols[i] = g_cols[i]; G.vals[i] = g_vals[i];
        G.cnt[i] = cnt + i * 256; G.fill[i] = fil + i * 256; G.rowptr[i] = rowp + i * 256;
        G.csr_col[i] = ccol + i * nnzp; G.csr_val[i] = cval + i * nnzp;
    }

    // CSR build + rowsums
    zero_k<<<(2 * 4 * 256 + 255) / 256, 256, 0, stream>>>(cnt, 2 * 4 * 256);
    count_k<<<dim3((nnz + 255) / 256, 4), 256, 0, stream>>>(G, nnz);
    scan_k<<<1, 64, 0, stream>>>(G);
    fill_k<<<dim3((nnz + 255) / 256, 4), 256, 0, stream>>>(G, nnz);
    rowsum_k<<<4, 256, 0, stream>>>(G, rs);

    // weight transpose+convert
    wconv_k<<<(384 * 416 + 255) / 256, 256, 0, stream>>>(W1, Wt1, 400, 300, 416, 384);
    wconv_k<<<(128 * 320 + 255) / 256, 256, 0, stream>>>(W2, Wt2, 300, 100, 320, 128);
    wconv_k<<<(384 * 128 + 255) / 256, 256, 0, stream>>>(Wd0, Wt3, 100, 300, 128, 384);
    wconv_k<<<(512 * 320 + 255) / 256, 256, 0, stream>>>(Wd1, Wt4, 300, 400, 320, 512);

    const int mt = M / 128;          // 510
    const int spmm_grid = NN * B;    // 65280 (swizzled 1D)
    float* tmpF = (float*)bufG;      // f32 [M,2] temp

    // L0: [2->400] g0, spmm-first.  H -> tmpF -> bufS[,416]
    spmm_f2_f32<<<(M + 255) / 256, 256, 0, stream>>>(H, tmpF, G.rowptr[0], G.csr_col[0], G.csr_val[0], M);
    gemm_k2_relu<<<(M * 208 + 255) / 256, 256, 0, stream>>>(tmpF, W0, b0, rs + 0, bufS, M, 400, 416);

    // L1: [400->300] g0, gemm-first. bufS(K416) -> bufG[,320] -> bufS[,320]
    gemm_mfma<<<dim3(mt, 3), 256, 0, stream>>>(bufS, Wt1, b1, nullptr, bufG, 416, 300, 320);
    spmm_bf16<<<spmm_grid, 128, 0, stream>>>(bufG, bufS, G.rowptr[0], G.csr_col[0], G.csr_val[0], 320, 1);

    // L2: [300->100] g1, gemm-first. bufS(K320) -> bufG[,128] -> bufS[,128]
    gemm_mfma<<<dim3(mt, 1), 256, 0, stream>>>(bufS, Wt2, b2, nullptr, bufG, 320, 100, 128);
    spmm_bf16<<<spmm_grid, 128, 0, stream>>>(bufG, bufS, G.rowptr[1], G.csr_col[1], G.csr_val[1], 128, 1);

    // L3: [100->300] g3, spmm-first. bufS(F128) -> bufG -> bufS[,320]
    spmm_bf16<<<spmm_grid, 128, 0, stream>>>(bufS, bufG, G.rowptr[3], G.csr_col[3], G.csr_val[3], 128, 0);
    gemm_mfma<<<dim3(mt, 3), 256, 0, stream>>>(bufG, Wt3, bd0, rs + 3 * 256, bufS, 128, 300, 320);

    // L4: [300->400] g2, spmm-first. bufS(F320) -> bufG -> bufS[,400]
    spmm_bf16<<<spmm_grid, 128, 0, stream>>>(bufS, bufG, G.rowptr[2], G.csr_col[2], G.csr_val[2], 320, 0);
    gemm_mfma<<<dim3(mt, 4), 256, 0, stream>>>(bufG, Wt4, bd1, rs + 2 * 256, bufS, 320, 400, 400);

    // L5: [400->2] g2.  bufS -> tmpF -> out
    gemm_n2_bf16<<<(M * 64 + 255) / 256, 256, 0, stream>>>(bufS, Wd2, bd2, tmpF, M, 400);
    spmm_final_k<<<(M + 255) / 256, 256, 0, stream>>>(tmpF, out, G.rowptr[2], G.csr_col[2], G.csr_val[2], M);
}

// Round 4
// 529.981 us; speedup vs baseline: 3.4015x; 1.1763x over previous
//
#include <hip/hip_runtime.h>
#include <hip/hip_bf16.h>

// 6 layers of relu(spmm(graph, x@W+b)), B=256, NN=255 nodes, M=B*NN=65280.
// R3: SpMM on matrix cores. Densify each graph to S[256,256] bf16 (atomic fp32
// scatter handles COO duplicates), keep activations alternating between
//   N-layout [(b,node), feat]  (input to dense GEMM)
//   T-layout [b, feat, node256] (input to spmm GEMM)
// Each MFMA GEMM writes the other layout straight from its epilogue.
// MFMA orientation: A-operand = small matrix (Wt or S), B-operand = activations,
// so epilogue stores are lane-contiguous (32B segments).

#define NN 255

typedef __attribute__((ext_vector_type(8))) short short8;
typedef __attribute__((ext_vector_type(4))) short short4v;
typedef __attribute__((ext_vector_type(4))) float floatx4;

__device__ __forceinline__ float bf2f(ushort u) {
    union { uint u; float f; } c; c.u = ((uint)u) << 16; return c.f;
}
__device__ __forceinline__ ushort f2bf(float f) {
    union { float f; uint u; } c; c.f = f;
    uint u = c.u + 0x7fff + ((c.u >> 16) & 1);
    return (ushort)(u >> 16);
}

// ---------------- CSR + dense-S build ----------------
struct Graphs {
    const int*   rows[4];
    const int*   cols[4];
    const float* vals[4];
    int*   cnt[4];
    int*   fill[4];
    int*   rowptr[4];
    int*   csr_col[4];
    float* csr_val[4];
};

__global__ void zero_k(int* p, int n) {
    int i = blockIdx.x * blockDim.x + threadIdx.x;
    if (i < n) p[i] = 0;
}

__global__ void count_k(Graphs g, int nnz) {
    int gi = blockIdx.y;
    int e = blockIdx.x * blockDim.x + threadIdx.x;
    if (e < nnz) atomicAdd(&g.cnt[gi][g.rows[gi][e]], 1);
}

__global__ void scan_k(Graphs g) {
    int gi = threadIdx.x;
    if (gi < 4) {
        const int* c = g.cnt[gi];
        int* rp = g.rowptr[gi];
        int s = 0;
        for (int i = 0; i < NN; ++i) { rp[i] = s; s += c[i]; }
        rp[NN] = s;
    }
}

__global__ void fill_k(Graphs g, int nnz) {
    int gi = blockIdx.y;
    int e = blockIdx.x * blockDim.x + threadIdx.x;
    if (e < nnz) {
        int r = g.rows[gi][e];
        int p = g.rowptr[gi][r] + atomicAdd(&g.fill[gi][r], 1);
        g.csr_col[gi][p] = g.cols[gi][e];
        g.csr_val[gi][p] = g.vals[gi][e];
    }
}

__global__ void rowsum_k(Graphs g, float* rs) {
    int gi = blockIdx.x, r = threadIdx.x;
    if (r < NN) {
        int s = g.rowptr[gi][r], e = g.rowptr[gi][r + 1];
        float a = 0.f;
        for (int i = s; i < e; ++i) a += g.csr_val[gi][i];
        rs[gi * 256 + r] = a;
    }
}

// dense S scatter: Sd[gi][r*256+c] += val  (fp32, duplicates accumulate)
__global__ void scatter_s_k(Graphs g, float* Sd, int nnz) {
    int gi = blockIdx.y;
    int e = blockIdx.x * blockDim.x + threadIdx.x;
    if (e < nnz)
        atomicAdd(&Sd[gi * 65536 + g.rows[gi][e] * 256 + g.cols[gi][e]], g.vals[gi][e]);
}

__global__ void sconv_k(const float* __restrict__ Sd, ushort* __restrict__ Sb, int n) {
    int i = blockIdx.x * blockDim.x + threadIdx.x;
    if (i < n) Sb[i] = f2bf(Sd[i]);
}

// ---- weight convert: W[K,N] f32 -> Wt[Npad,Kpad] bf16 (transposed, zero-pad) ----
__global__ void wconv_k(const float* __restrict__ W, ushort* __restrict__ Wt,
                        int K, int N, int Kpad, int Npad) {
    int idx = blockIdx.x * blockDim.x + threadIdx.x;
    if (idx >= Npad * Kpad) return;
    int n = idx / Kpad, k = idx - n * Kpad;
    float v = (n < N && k < K) ? W[(size_t)k * N + n] : 0.f;
    Wt[idx] = f2bf(v);
}

// ---------------- L0 spmm: F=2, f32 in (H), f32 out ----------------
__global__ __launch_bounds__(256) void spmm_f2_f32(const float* __restrict__ H,
                                                   float* __restrict__ T,
                                                   const int* __restrict__ rowptr,
                                                   const int* __restrict__ cols,
                                                   const float* __restrict__ vals,
                                                   int total) {
    int tt = blockIdx.x * blockDim.x + threadIdx.x;
    if (tt >= total) return;
    int r = tt % NN, b = tt / NN;
    int s = rowptr[r], e = rowptr[r + 1];
    const float* Hb = H + (size_t)b * NN * 2;
    float a0 = 0.f, a1 = 0.f;
    for (int i = s; i < e; ++i) {
        float v = vals[i]; int c = cols[i];
        a0 = fmaf(v, Hb[c * 2], a0);
        a1 = fmaf(v, Hb[c * 2 + 1], a1);
    }
    T[(size_t)tt * 2] = a0;
    T[(size_t)tt * 2 + 1] = a1;
}

// -------- L0 GEMM (K=2) with relu(acc + rs[r]*b[n]), bf16 out stride 416 --------
__global__ __launch_bounds__(256) void gemm_k2_relu(const float* __restrict__ T,
                                                    const float* __restrict__ W,
                                                    const float* __restrict__ bias,
                                                    const float* __restrict__ rs,
                                                    ushort* __restrict__ Y,
                                                    int M, int N, int Nstride) {
    int half = Nstride >> 1;
    int idx = blockIdx.x * blockDim.x + threadIdx.x;
    if (idx >= M * half) return;
    int m = idx / half, n2 = (idx - m * half) * 2;
    uint o = 0;
    if (n2 < N) {
        float x0 = T[m * 2], x1 = T[m * 2 + 1];
        float rsm = rs[m % NN];
        float y0 = fmaf(x0, W[n2],     fmaf(x1, W[N + n2],     rsm * bias[n2]));
        float y1 = fmaf(x0, W[n2 + 1], fmaf(x1, W[N + n2 + 1], rsm * bias[n2 + 1]));
        y0 = fmaxf(y0, 0.f); y1 = fmaxf(y1, 0.f);
        o = (uint)f2bf(y0) | ((uint)f2bf(y1) << 16);
    }
    ((uint*)Y)[idx] = o;
}

// =======================================================================
// Shared MFMA body: A = small matrix [>=m-tiles*128, Kpad], B = big rows.
// 128x128 tile, 4 waves, BK=32, LDS stride 36 (conflict-free).
// D rows (i,quad,reg) = A rows; D cols (j,frow) = B rows.
// =======================================================================
#define LSTR 36

__device__ __forceinline__ short8 ld_frag(const ushort* p) {
    union { short8 v; short4v h[2]; } u;
    u.h[0] = *(const short4v*)p;
    u.h[1] = *(const short4v*)(p + 4);
    return u.v;
}

#define MFMA_BODY(Asrc, Bsrc)                                              \
    __shared__ ushort As[128 * LSTR];                                      \
    __shared__ ushort Bs[128 * LSTR];                                      \
    int t = threadIdx.x;                                                   \
    int m0 = blockIdx.x * 128, n0 = blockIdx.y * 128;                      \
    int srow = t >> 1, scol = (t & 1) * 16;                                \
    const uint4* Ag = (const uint4*)(Asrc + (size_t)(m0 + srow) * Kpad + scol); \
    const uint4* Bg = (const uint4*)(Bsrc + (size_t)(n0 + srow) * Kpad + scol); \
    uint2* Aw = (uint2*)&As[srow * LSTR + scol];                           \
    uint2* Bw = (uint2*)&Bs[srow * LSTR + scol];                           \
    int wave = t >> 6, lane = t & 63;                                      \
    int wm = (wave >> 1) * 64, wn = (wave & 1) * 64;                       \
    int frow = lane & 15, quad = lane >> 4, fq = quad * 8;                 \
    const ushort* Ab = &As[(wm + frow) * LSTR + fq];                       \
    const ushort* Bb = &Bs[(wn + frow) * LSTR + fq];                       \
    floatx4 acc[4][4];                                                     \
    _Pragma("unroll")                                                      \
    for (int i = 0; i < 4; ++i)                                            \
        _Pragma("unroll")                                                  \
        for (int j = 0; j < 4; ++j) acc[i][j] = (floatx4)0.f;              \
    int nk = Kpad >> 5;                                                    \
    uint4 a0 = Ag[0], a1 = Ag[1];                                          \
    uint4 b0 = Bg[0], b1 = Bg[1];                                          \
    Ag += 4; Bg += 4;                                                      \
    for (int ks = 0; ks < nk; ++ks) {                                      \
        __syncthreads();                                                   \
        Aw[0] = make_uint2(a0.x, a0.y); Aw[1] = make_uint2(a0.z, a0.w);    \
        Aw[2] = make_uint2(a1.x, a1.y); Aw[3] = make_uint2(a1.z, a1.w);    \
        Bw[0] = make_uint2(b0.x, b0.y); Bw[1] = make_uint2(b0.z, b0.w);    \
        Bw[2] = make_uint2(b1.x, b1.y); Bw[3] = make_uint2(b1.z, b1.w);    \
        __syncthreads();                                                   \
        if (ks + 1 < nk) {                                                 \
            a0 = Ag[0]; a1 = Ag[1]; b0 = Bg[0]; b1 = Bg[1];                \
            Ag += 4; Bg += 4;                                              \
        }                                                                  \
        short8 af[4], bf[4];                                               \
        _Pragma("unroll")                                                  \
        for (int i = 0; i < 4; ++i) {                                      \
            af[i] = ld_frag(Ab + i * 16 * LSTR);                           \
            bf[i] = ld_frag(Bb + i * 16 * LSTR);                           \
        }                                                                  \
        _Pragma("unroll")                                                  \
        for (int i = 0; i < 4; ++i)                                        \
            _Pragma("unroll")                                              \
            for (int j = 0; j < 4; ++j)                                    \
                acc[i][j] = __builtin_amdgcn_mfma_f32_16x16x32_bf16(af[i], bf[j], acc[i][j], 0, 0, 0); \
    }

// Dense feat-transform: B rows = N-layout acts [(b,node), Kpad]; A = Wt[Npad,Kpad].
// Out: T-layout  T[(b*Nfeat + gn)*256 + node] = acc + bias[gn]   (no relu)
__global__ __launch_bounds__(256) void dense_mfma_T(const ushort* __restrict__ Wt,
                                                    const ushort* __restrict__ X,
                                                    const float* __restrict__ bias,
                                                    ushort* __restrict__ T,
                                                    int Kpad, int Nfeat) {
    MFMA_BODY(Wt, X)
    #pragma unroll
    for (int j = 0; j < 4; ++j) {
        int mrow = n0 + wn + j * 16 + frow;       // (b, node)
        int b = mrow / NN, node = mrow - b * NN;
        int base = (b * Nfeat) * 256 + node;
        #pragma unroll
        for (int i = 0; i < 4; ++i) {
            int gn0 = m0 + wm + i * 16 + quad * 4;
            #pragma unroll
            for (int r = 0; r < 4; ++r) {
                int gn = gn0 + r;
                if (gn < Nfeat)
                    T[base + gn * 256] = f2bf(acc[i][j][r] + bias[gn]);
            }
        }
    }
}

// SpMM: B rows = T-layout acts [(b*F + f), 256]; A = S[256,256].
// Out: N-layout  Z[(b*NN + r)*Fs + f] = relu(acc)    (skip r==255)
__global__ __launch_bounds__(256) void spmm_mfma_N(const ushort* __restrict__ S,
                                                   const ushort* __restrict__ X,
                                                   ushort* __restrict__ Z,
                                                   int Kpad, int F, int Fs) {
    MFMA_BODY(S, X)
    #pragma unroll
    for (int j = 0; j < 4; ++j) {
        int mrow = n0 + wn + j * 16 + frow;       // (b, f)
        int b = mrow / F, f = mrow - b * F;
        int base = b * NN * Fs + f;
        #pragma unroll
        for (int i = 0; i < 4; ++i) {
            int r0 = m0 + wm + i * 16 + quad * 4;
            #pragma unroll
            for (int r = 0; r < 4; ++r) {
                int node = r0 + r;
                if (node < NN)
                    Z[base + node * Fs] = f2bf(fmaxf(acc[i][j][r], 0.f));
            }
        }
    }
}

// ---------------- L5 GEMM (N=2): wave/row, bf16 in, f32 out ----------------
__global__ __launch_bounds__(256) void gemm_n2_bf16(const ushort* __restrict__ X,
                                                    const float* __restrict__ W,
                                                    const float* __restrict__ bias,
                                                    float* __restrict__ Y,
                                                    int M, int K) {
    int wv = (blockIdx.x * blockDim.x + threadIdx.x) >> 6;
    int lane = threadIdx.x & 63;
    if (wv >= M) return;
    const uint* Xr = (const uint*)(X + (size_t)wv * K);
    int K2 = K >> 1;
    float a0 = 0.f, a1 = 0.f;
    for (int k2 = lane; k2 < K2; k2 += 64) {
        uint p = Xr[k2];
        float x0 = bf2f((ushort)(p & 0xffffu)), x1 = bf2f((ushort)(p >> 16));
        float4 w = ((const float4*)W)[k2];
        a0 = fmaf(x0, w.x, fmaf(x1, w.z, a0));
        a1 = fmaf(x0, w.y, fmaf(x1, w.w, a1));
    }
    #pragma unroll
    for (int off = 32; off; off >>= 1) {
        a0 += __shfl_down(a0, off);
        a1 += __shfl_down(a1, off);
    }
    if (lane == 0) {
        Y[(size_t)wv * 2]     = a0 + bias[0];
        Y[(size_t)wv * 2 + 1] = a1 + bias[1];
    }
}

// ---------------- final SpMM (F=2) + relu, f32 in, f32 out ----------------
__global__ __launch_bounds__(256) void spmm_final_k(const float* __restrict__ Y,
                                                    float* __restrict__ Z,
                                                    const int* __restrict__ rowptr,
                                                    const int* __restrict__ cols,
                                                    const float* __restrict__ vals,
                                                    int total) {
    int tt = blockIdx.x * blockDim.x + threadIdx.x;
    if (tt >= total) return;
    int r = tt % NN, b = tt / NN;
    int s = rowptr[r], e = rowptr[r + 1];
    const float* Yb = Y + (size_t)b * NN * 2;
    float a0 = 0.f, a1 = 0.f;
    for (int i = s; i < e; ++i) {
        float v = vals[i]; int c = cols[i];
        a0 = fmaf(v, Yb[c * 2], a0);
        a1 = fmaf(v, Yb[c * 2 + 1], a1);
    }
    Z[(size_t)tt * 2]     = fmaxf(a0, 0.f);
    Z[(size_t)tt * 2 + 1] = fmaxf(a1, 0.f);
}

extern "C" void kernel_launch(void* const* d_in, const int* in_sizes, int n_in,
                              void* d_out, int out_size, void* d_ws, size_t ws_size,
                              hipStream_t stream) {
    const float* H = (const float*)d_in[0];
    const int*   g_rows[4] = {(const int*)d_in[1], (const int*)d_in[4], (const int*)d_in[7], (const int*)d_in[10]};
    const int*   g_cols[4] = {(const int*)d_in[2], (const int*)d_in[5], (const int*)d_in[8], (const int*)d_in[11]};
    const float* g_vals[4] = {(const float*)d_in[3], (const float*)d_in[6], (const float*)d_in[9], (const float*)d_in[12]};
    const float* W0  = (const float*)d_in[13]; const float* b0  = (const float*)d_in[14];
    const float* W1  = (const float*)d_in[15]; const float* b1  = (const float*)d_in[16];
    const float* W2  = (const float*)d_in[17]; const float* b2  = (const float*)d_in[18];
    const float* Wd0 = (const float*)d_in[19]; const float* bd0 = (const float*)d_in[20];
    const float* Wd1 = (const float*)d_in[21]; const float* bd1 = (const float*)d_in[22];
    const float* Wd2 = (const float*)d_in[23]; const float* bd2 = (const float*)d_in[24];
    float* out = (float*)d_out;

    const int nnz = in_sizes[1];
    const int B   = in_sizes[0] / (NN * 2);   // 256
    const int M   = B * NN;                   // 65280 = 510*128

    // ---- workspace (ushort units) ----
    ushort* bufN = (ushort*)d_ws;                    // N-layout [(b,node), 416]
    ushort* bufT = bufN + (size_t)M * 416;           // T-layout [b, 400, 256] (also f32 [M,2] tmp)
    ushort* Wt1 = bufT + (size_t)B * 400 * 256;      // [384,416]
    ushort* Wt2 = Wt1 + 384 * 416;                   // [128,320]
    ushort* Wt3 = Wt2 + 128 * 320;                   // [384,128]
    ushort* Wt4 = Wt3 + 384 * 128;                   // [512,320]
    ushort* Sb  = Wt4 + 512 * 320;                   // 4 x [256,256] bf16
    float*  Sd  = (float*)(Sb + 4 * 65536);          // 4 x [256,256] f32
    float*  rs  = Sd + 4 * 65536;                    // [4][256]
    int*    cnt = (int*)(rs + 4 * 256);
    int*    fil = cnt + 4 * 256;
    int*    rowp = fil + 4 * 256;
    const int nnzp = (nnz + 63) & ~63;
    int*    ccol = rowp + 4 * 256;
    float*  cval = (float*)(ccol + 4 * nnzp);

    Graphs G;
    for (int i = 0; i < 4; ++i) {
        G.rows[i] = g_rows[i]; G.cols[i] = g_cols[i]; G.vals[i] = g_vals[i];
        G.cnt[i] = cnt + i * 256; G.fill[i] = fil + i * 256; G.rowptr[i] = rowp + i * 256;
        G.csr_col[i] = ccol + i * nnzp; G.csr_val[i] = cval + i * nnzp;
    }

    // CSR (for the two scalar F=2 spmms + rowsum) and dense S build
    zero_k<<<(2 * 4 * 256 + 255) / 256, 256, 0, stream>>>(cnt, 2 * 4 * 256);
    zero_k<<<(4 * 65536 + 255) / 256, 256, 0, stream>>>((int*)Sd, 4 * 65536);
    count_k<<<dim3((nnz + 255) / 256, 4), 256, 0, stream>>>(G, nnz);
    scatter_s_k<<<dim3((nnz + 255) / 256, 4), 256, 0, stream>>>(G, Sd, nnz);
    scan_k<<<1, 64, 0, stream>>>(G);
    fill_k<<<dim3((nnz + 255) / 256, 4), 256, 0, stream>>>(G, nnz);
    rowsum_k<<<4, 256, 0, stream>>>(G, rs);
    sconv_k<<<(4 * 65536 + 255) / 256, 256, 0, stream>>>(Sd, Sb, 4 * 65536);

    // weight transpose+convert
    wconv_k<<<(384 * 416 + 255) / 256, 256, 0, stream>>>(W1, Wt1, 400, 300, 416, 384);
    wconv_k<<<(128 * 320 + 255) / 256, 256, 0, stream>>>(W2, Wt2, 300, 100, 320, 128);
    wconv_k<<<(384 * 128 + 255) / 256, 256, 0, stream>>>(Wd0, Wt3, 100, 300, 128, 384);
    wconv_k<<<(512 * 320 + 255) / 256, 256, 0, stream>>>(Wd1, Wt4, 300, 400, 320, 512);

    const int mt = M / 128;          // 510
    float* tmpF = (float*)bufT;

    // L0: [2->400] g0, commuted (spmm on F=2 first).  H -> tmpF -> bufN[,416]
    spmm_f2_f32<<<(M + 255) / 256, 256, 0, stream>>>(H, tmpF, G.rowptr[0], G.csr_col[0], G.csr_val[0], M);
    gemm_k2_relu<<<(M * 208 + 255) / 256, 256, 0, stream>>>(tmpF, W0, b0, rs + 0, bufN, M, 400, 416);

    // L1: [400->300] g0.  bufN(K416) -> bufT[b,300,256] -> bufN[,320]
    dense_mfma_T<<<dim3(3, mt), 256, 0, stream>>>(Wt1, bufN, b1, bufT, 416, 300);
    spmm_mfma_N<<<dim3(2, B * 300 / 128), 256, 0, stream>>>(Sb + 0 * 65536, bufT, bufN, 256, 300, 320);

    // L2: [300->100] g1.  bufN(K320) -> bufT[b,100,256] -> bufN[,128]
    dense_mfma_T<<<dim3(1, mt), 256, 0, stream>>>(Wt2, bufN, b2, bufT, 320, 100);
    spmm_mfma_N<<<dim3(2, B * 100 / 128), 256, 0, stream>>>(Sb + 1 * 65536, bufT, bufN, 256, 100, 128);

    // L3: [100->300] g3.  bufN(K128) -> bufT[b,300,256] -> bufN[,320]
    dense_mfma_T<<<dim3(3, mt), 256, 0, stream>>>(Wt3, bufN, bd0, bufT, 128, 300);
    spmm_mfma_N<<<dim3(2, B * 300 / 128), 256, 0, stream>>>(Sb + 3 * 65536, bufT, bufN, 256, 300, 320);

    // L4: [300->400] g2.  bufN(K320) -> bufT[b,400,256] -> bufN[,400]
    dense_mfma_T<<<dim3(4, mt), 256, 0, stream>>>(Wt4, bufN, bd1, bufT, 320, 400);
    spmm_mfma_N<<<dim3(2, B * 400 / 128), 256, 0, stream>>>(Sb + 2 * 65536, bufT, bufN, 256, 400, 400);

    // L5: [400->2] g2.  bufN -> tmpF -> out
    gemm_n2_bf16<<<(M * 64 + 255) / 256, 256, 0, stream>>>(bufN, Wd2, bd2, tmpF, M, 400);
    spmm_final_k<<<(M + 255) / 256, 256, 0, stream>>>(tmpF, out, G.rowptr[2], G.csr_col[2], G.csr_val[2], M);
}

// Round 5
// 492.376 us; speedup vs baseline: 3.6613x; 1.0764x over previous
//
#include <hip/hip_runtime.h>
#include <hip/hip_bf16.h>

// 6 layers of relu(spmm(graph, x@W+b)), B=256, NN=255 nodes.
// R4: LDS-transpose epilogues (coalesced dwordx4 stores, no partial-line RMW),
// XCD-swizzled 1D grids, batch-padded layouts:
//   N-layout: [b*256 + node][Fs]   (node 255 = dead zero row)
//   T-layout: [b*FsT + f][256]     (f in [Nfeat,FsT) = dead garbage rows;
//                                   killed by zero weight K-pad downstream)

#define NN 255
#define LSTR 36   // K-loop LDS row stride (ushorts)
#define TSTR 72   // transpose-tile stride (ushorts) = 144 B, 16B-aligned rows

typedef __attribute__((ext_vector_type(8))) short short8;
typedef __attribute__((ext_vector_type(4))) short short4v;
typedef __attribute__((ext_vector_type(4))) float floatx4;

__device__ __forceinline__ float bf2f(ushort u) {
    union { uint u; float f; } c; c.u = ((uint)u) << 16; return c.f;
}
__device__ __forceinline__ ushort f2bf(float f) {
    union { float f; uint u; } c; c.f = f;
    uint u = c.u + 0x7fff + ((c.u >> 16) & 1);
    return (ushort)(u >> 16);
}

// ---------------- CSR + dense-S build ----------------
struct Graphs {
    const int*   rows[4];
    const int*   cols[4];
    const float* vals[4];
    int*   cnt[4];
    int*   fill[4];
    int*   rowptr[4];
    int*   csr_col[4];
    float* csr_val[4];
};

__global__ void zero_k(int* p, int n) {
    int i = blockIdx.x * blockDim.x + threadIdx.x;
    if (i < n) p[i] = 0;
}

__global__ void count_k(Graphs g, int nnz) {
    int gi = blockIdx.y;
    int e = blockIdx.x * blockDim.x + threadIdx.x;
    if (e < nnz) atomicAdd(&g.cnt[gi][g.rows[gi][e]], 1);
}

__global__ void scan_k(Graphs g) {
    int gi = threadIdx.x;
    if (gi < 4) {
        const int* c = g.cnt[gi];
        int* rp = g.rowptr[gi];
        int s = 0;
        for (int i = 0; i < NN; ++i) { rp[i] = s; s += c[i]; }
        rp[NN] = s;
    }
}

__global__ void fill_k(Graphs g, int nnz) {
    int gi = blockIdx.y;
    int e = blockIdx.x * blockDim.x + threadIdx.x;
    if (e < nnz) {
        int r = g.rows[gi][e];
        int p = g.rowptr[gi][r] + atomicAdd(&g.fill[gi][r], 1);
        g.csr_col[gi][p] = g.cols[gi][e];
        g.csr_val[gi][p] = g.vals[gi][e];
    }
}

__global__ void rowsum_k(Graphs g, float* rs) {
    int gi = blockIdx.x, r = threadIdx.x;
    if (r < NN) {
        int s = g.rowptr[gi][r], e = g.rowptr[gi][r + 1];
        float a = 0.f;
        for (int i = s; i < e; ++i) a += g.csr_val[gi][i];
        rs[gi * 256 + r] = a;
    }
}

__global__ void scatter_s_k(Graphs g, float* Sd, int nnz) {
    int gi = blockIdx.y;
    int e = blockIdx.x * blockDim.x + threadIdx.x;
    if (e < nnz)
        atomicAdd(&Sd[gi * 65536 + g.rows[gi][e] * 256 + g.cols[gi][e]], g.vals[gi][e]);
}

__global__ void sconv_k(const float* __restrict__ Sd, ushort* __restrict__ Sb, int n) {
    int i = blockIdx.x * blockDim.x + threadIdx.x;
    if (i < n) Sb[i] = f2bf(Sd[i]);
}

__global__ void wconv_k(const float* __restrict__ W, ushort* __restrict__ Wt,
                        int K, int N, int Kpad, int Npad) {
    int idx = blockIdx.x * blockDim.x + threadIdx.x;
    if (idx >= Npad * Kpad) return;
    int n = idx / Kpad, k = idx - n * Kpad;
    float v = (n < N && k < K) ? W[(size_t)k * N + n] : 0.f;
    Wt[idx] = f2bf(v);
}

// ---------------- L0 spmm: F=2, f32 in (H, compact M=B*255), f32 out ----------------
__global__ __launch_bounds__(256) void spmm_f2_f32(const float* __restrict__ H,
                                                   float* __restrict__ T,
                                                   const int* __restrict__ rowptr,
                                                   const int* __restrict__ cols,
                                                   const float* __restrict__ vals,
                                                   int total) {
    int tt = blockIdx.x * blockDim.x + threadIdx.x;
    if (tt >= total) return;
    int r = tt % NN, b = tt / NN;
    int s = rowptr[r], e = rowptr[r + 1];
    const float* Hb = H + (size_t)b * NN * 2;
    float a0 = 0.f, a1 = 0.f;
    for (int i = s; i < e; ++i) {
        float v = vals[i]; int c = cols[i];
        a0 = fmaf(v, Hb[c * 2], a0);
        a1 = fmaf(v, Hb[c * 2 + 1], a1);
    }
    T[(size_t)tt * 2] = a0;
    T[(size_t)tt * 2 + 1] = a1;
}

// -------- L0 GEMM (K=2): relu(acc + rs[node]*b[n]) -> padded N-layout [b*256+node][416] --------
__global__ __launch_bounds__(256) void gemm_k2_relu(const float* __restrict__ T,
                                                    const float* __restrict__ W,
                                                    const float* __restrict__ bias,
                                                    const float* __restrict__ rs,
                                                    ushort* __restrict__ Y,
                                                    int Mp, int N, int Ns) {
    int half = Ns >> 1;    // 208
    int idx = blockIdx.x * blockDim.x + threadIdx.x;
    if (idx >= Mp * half) return;
    int m = idx / half, n2 = (idx - m * half) * 2;
    int node = m & 255, b = m >> 8;
    uint o = 0;
    if (n2 < N && node < NN) {
        int mc = b * NN + node;
        float x0 = T[mc * 2], x1 = T[mc * 2 + 1];
        float rsm = rs[node];
        float y0 = fmaf(x0, W[n2],     fmaf(x1, W[N + n2],     rsm * bias[n2]));
        float y1 = fmaf(x0, W[n2 + 1], fmaf(x1, W[N + n2 + 1], rsm * bias[n2 + 1]));
        o = (uint)f2bf(fmaxf(y0, 0.f)) | ((uint)f2bf(fmaxf(y1, 0.f)) << 16);
    }
    ((uint*)Y)[idx] = o;
}

// =======================================================================
// MFMA body: A = small matrix rows [m0..m0+127, Kpad], B = big rows [n0..].
// 128x128 tile, 4 waves, BK=32. D rows = A rows (i,quad,reg); D cols = B rows (j,frow).
// =======================================================================
__device__ __forceinline__ short8 ld_frag(const ushort* p) {
    union { short8 v; short4v h[2]; } u;
    u.h[0] = *(const short4v*)p;
    u.h[1] = *(const short4v*)(p + 4);
    return u.v;
}

// decode XCD-swizzled 1D grid: all nft A-tiles of one B-row-tile share li%8 (same XCD)
__device__ __forceinline__ bool decode_tile(int li, int nft, int nrt, int& m0, int& n0) {
    int x = li & 7, r = li >> 3;
    int ft = r % nft, q = r / nft;
    int rt = q * 8 + x;
    if (rt >= nrt) return false;
    m0 = ft * 128; n0 = rt * 128;
    return true;
}

#define MFMA_BODY(Asrc, Bsrc)                                              \
    ushort* As = smem;                                                     \
    ushort* Bs = smem + 128 * LSTR;                                        \
    int t = threadIdx.x;                                                   \
    int srow = t >> 1, scol = (t & 1) * 16;                                \
    const uint4* Ag = (const uint4*)(Asrc + (size_t)(m0 + srow) * Kpad + scol); \
    const uint4* Bg = (const uint4*)(Bsrc + (size_t)(n0 + srow) * Kpad + scol); \
    uint2* Aw = (uint2*)&As[srow * LSTR + scol];                           \
    uint2* Bw = (uint2*)&Bs[srow * LSTR + scol];                           \
    int wave = t >> 6, lane = t & 63;                                      \
    int wm = (wave >> 1) * 64, wn = (wave & 1) * 64;                       \
    int frow = lane & 15, quad = lane >> 4, fq = quad * 8;                 \
    const ushort* Ab = &As[(wm + frow) * LSTR + fq];                       \
    const ushort* Bb = &Bs[(wn + frow) * LSTR + fq];                       \
    floatx4 acc[4][4];                                                     \
    _Pragma("unroll")                                                      \
    for (int i = 0; i < 4; ++i)                                            \
        _Pragma("unroll")                                                  \
        for (int j = 0; j < 4; ++j) acc[i][j] = (floatx4)0.f;              \
    int nk = Kpad >> 5;                                                    \
    uint4 a0 = Ag[0], a1 = Ag[1];                                          \
    uint4 b0 = Bg[0], b1 = Bg[1];                                          \
    Ag += 4; Bg += 4;                                                      \
    for (int ks = 0; ks < nk; ++ks) {                                      \
        __syncthreads();                                                   \
        Aw[0] = make_uint2(a0.x, a0.y); Aw[1] = make_uint2(a0.z, a0.w);    \
        Aw[2] = make_uint2(a1.x, a1.y); Aw[3] = make_uint2(a1.z, a1.w);    \
        Bw[0] = make_uint2(b0.x, b0.y); Bw[1] = make_uint2(b0.z, b0.w);    \
        Bw[2] = make_uint2(b1.x, b1.y); Bw[3] = make_uint2(b1.z, b1.w);    \
        __syncthreads();                                                   \
        if (ks + 1 < nk) {                                                 \
            a0 = Ag[0]; a1 = Ag[1]; b0 = Bg[0]; b1 = Bg[1];                \
            Ag += 4; Bg += 4;                                              \
        }                                                                  \
        short8 af[4], bf[4];                                               \
        _Pragma("unroll")                                                  \
        for (int i = 0; i < 4; ++i) {                                      \
            af[i] = ld_frag(Ab + i * 16 * LSTR);                           \
            bf[i] = ld_frag(Bb + i * 16 * LSTR);                           \
        }                                                                  \
        _Pragma("unroll")                                                  \
        for (int i = 0; i < 4; ++i)                                        \
            _Pragma("unroll")                                              \
            for (int j = 0; j < 4; ++j)                                    \
                acc[i][j] = __builtin_amdgcn_mfma_f32_16x16x32_bf16(af[i], bf[j], acc[i][j], 0, 0, 0); \
    }

// Dense: A=Wt[Npad,Kpad], B=N-layout X[b*256+node][Kpad].
// Out T-layout: T[(b*FsT+gn)*256 + node] = acc + bias[gn], via LDS transpose.
__global__ __launch_bounds__(256) void dense_mfma_T(const ushort* __restrict__ Wt,
                                                    const ushort* __restrict__ X,
                                                    const float* __restrict__ bias,
                                                    ushort* __restrict__ T,
                                                    int Kpad, int Nfeat, int FsT,
                                                    int nft, int nrt) {
    __shared__ ushort smem[2 * 128 * LSTR];
    int m0, n0;
    if (!decode_tile(blockIdx.x, nft, nrt, m0, n0)) return;
    MFMA_BODY(Wt, X)
    ushort* Ts = smem;
    int trow = t >> 1, tc0 = (t & 1) * 32;
    #pragma unroll
    for (int p = 0; p < 2; ++p) {
        __syncthreads();
        if ((wave & 1) == p) {
            #pragma unroll
            for (int i = 0; i < 4; ++i)
                #pragma unroll
                for (int r = 0; r < 4; ++r) {
                    int row = wm + i * 16 + quad * 4 + r;
                    float bv = (m0 + row < Nfeat) ? bias[m0 + row] : 0.f;
                    #pragma unroll
                    for (int j = 0; j < 4; ++j)
                        Ts[row * TSTR + j * 16 + frow] = f2bf(acc[i][j][r] + bv);
                }
        }
        __syncthreads();
        int gn = m0 + trow;
        if (gn < Nfeat) {
            const uint4* src = (const uint4*)(Ts + trow * TSTR + tc0);
            int mbase = n0 + p * 64 + tc0;
            #pragma unroll
            for (int c = 0; c < 4; ++c) {
                int mrow = mbase + c * 8;
                int b = mrow >> 8, node = mrow & 255;
                *(uint4*)(T + (((size_t)(b * FsT + gn)) << 8) + node) = src[c];
            }
        }
    }
}

// SpMM: A=S[256,256], B=T-layout X[b*FsT+f][256].
// Out N-layout: Z[(b*256+node)*FsT + f] = relu(acc), via LDS transpose.
__global__ __launch_bounds__(256) void spmm_mfma_N(const ushort* __restrict__ S,
                                                   const ushort* __restrict__ X,
                                                   ushort* __restrict__ Z,
                                                   int FsT, int nrt) {
    __shared__ ushort smem[2 * 128 * LSTR];
    int m0, n0;
    if (!decode_tile(blockIdx.x, 2, nrt, m0, n0)) return;
    const int Kpad = 256;
    MFMA_BODY(S, X)
    ushort* Ts = smem;
    int trow = t >> 1, tc0 = (t & 1) * 32;
    #pragma unroll
    for (int p = 0; p < 2; ++p) {
        __syncthreads();
        if ((wave & 1) == p) {
            #pragma unroll
            for (int i = 0; i < 4; ++i)
                #pragma unroll
                for (int r = 0; r < 4; ++r) {
                    int row = wm + i * 16 + quad * 4 + r;
                    #pragma unroll
                    for (int j = 0; j < 4; ++j)
                        Ts[row * TSTR + j * 16 + frow] = f2bf(fmaxf(acc[i][j][r], 0.f));
                }
        }
        __syncthreads();
        int node = m0 + trow;
        const uint4* src = (const uint4*)(Ts + trow * TSTR + tc0);
        int cbase = n0 + p * 64 + tc0;
        #pragma unroll
        for (int c = 0; c < 4; ++c) {
            int mcol = cbase + c * 8;
            int b = mcol / FsT;              // FsT multiple of 8 -> chunk stays in one b
            int f = mcol - b * FsT;
            *(uint4*)(Z + ((size_t)((b << 8) + node)) * FsT + f) = src[c];
        }
    }
}

// ---------------- L5 GEMM (N=2): wave/row over padded M'=B*256, bf16 in, f32 out ----------------
__global__ __launch_bounds__(256) void gemm_n2_bf16(const ushort* __restrict__ X,
                                                    const float* __restrict__ W,
                                                    const float* __restrict__ bias,
                                                    float* __restrict__ Y,
                                                    int Mp, int K) {
    int wv = (blockIdx.x * blockDim.x + threadIdx.x) >> 6;
    int lane = threadIdx.x & 63;
    if (wv >= Mp) return;
    const uint* Xr = (const uint*)(X + (size_t)wv * K);
    int K2 = K >> 1;
    float a0 = 0.f, a1 = 0.f;
    for (int k2 = lane; k2 < K2; k2 += 64) {
        uint p = Xr[k2];
        float x0 = bf2f((ushort)(p & 0xffffu)), x1 = bf2f((ushort)(p >> 16));
        float4 w = ((const float4*)W)[k2];
        a0 = fmaf(x0, w.x, fmaf(x1, w.z, a0));
        a1 = fmaf(x0, w.y, fmaf(x1, w.w, a1));
    }
    #pragma unroll
    for (int off = 32; off; off >>= 1) {
        a0 += __shfl_down(a0, off);
        a1 += __shfl_down(a1, off);
    }
    if (lane == 0) {
        Y[(size_t)wv * 2]     = a0 + bias[0];
        Y[(size_t)wv * 2 + 1] = a1 + bias[1];
    }
}

// ---------------- final SpMM (F=2) + relu: padded f32 in [b*256+c], compact out ----------------
__global__ __launch_bounds__(256) void spmm_final_k(const float* __restrict__ Y,
                                                    float* __restrict__ Z,
                                                    const int* __restrict__ rowptr,
                                                    const int* __restrict__ cols,
                                                    const float* __restrict__ vals,
                                                    int total) {
    int tt = blockIdx.x * blockDim.x + threadIdx.x;
    if (tt >= total) return;
    int r = tt % NN, b = tt / NN;
    int s = rowptr[r], e = rowptr[r + 1];
    const float* Yb = Y + ((size_t)b << 9);
    float a0 = 0.f, a1 = 0.f;
    for (int i = s; i < e; ++i) {
        float v = vals[i]; int c = cols[i];
        a0 = fmaf(v, Yb[c * 2], a0);
        a1 = fmaf(v, Yb[c * 2 + 1], a1);
    }
    Z[(size_t)tt * 2]     = fmaxf(a0, 0.f);
    Z[(size_t)tt * 2 + 1] = fmaxf(a1, 0.f);
}

extern "C" void kernel_launch(void* const* d_in, const int* in_sizes, int n_in,
                              void* d_out, int out_size, void* d_ws, size_t ws_size,
                              hipStream_t stream) {
    const float* H = (const float*)d_in[0];
    const int*   g_rows[4] = {(const int*)d_in[1], (const int*)d_in[4], (const int*)d_in[7], (const int*)d_in[10]};
    const int*   g_cols[4] = {(const int*)d_in[2], (const int*)d_in[5], (const int*)d_in[8], (const int*)d_in[11]};
    const float* g_vals[4] = {(const float*)d_in[3], (const float*)d_in[6], (const float*)d_in[9], (const float*)d_in[12]};
    const float* W0  = (const float*)d_in[13]; const float* b0  = (const float*)d_in[14];
    const float* W1  = (const float*)d_in[15]; const float* b1  = (const float*)d_in[16];
    const float* W2  = (const float*)d_in[17]; const float* b2  = (const float*)d_in[18];
    const float* Wd0 = (const float*)d_in[19]; const float* bd0 = (const float*)d_in[20];
    const float* Wd1 = (const float*)d_in[21]; const float* bd1 = (const float*)d_in[22];
    const float* Wd2 = (const float*)d_in[23]; const float* bd2 = (const float*)d_in[24];
    float* out = (float*)d_out;

    const int nnz = in_sizes[1];
    const int B   = in_sizes[0] / (NN * 2);   // 256
    const int M   = B * NN;                   // 65280 (compact)
    const int Mp  = B * 256;                  // 65536 (padded)

    // ---- workspace (ushort units) ----
    ushort* bufN = (ushort*)d_ws;                    // N-layout [Mp, <=416]
    ushort* bufT = bufN + (size_t)Mp * 416;          // T-layout [B*FsT, 256], FsT<=416 (also f32 [M,2]/[Mp,2] tmp)
    ushort* Wt1 = bufT + (size_t)B * 416 * 256;      // [384,416]
    ushort* Wt2 = Wt1 + 384 * 416;                   // [128,320]
    ushort* Wt3 = Wt2 + 128 * 320;                   // [384,128]
    ushort* Wt4 = Wt3 + 384 * 128;                   // [512,320]
    ushort* Sb  = Wt4 + 512 * 320;                   // 4 x [256,256] bf16
    float*  Sd  = (float*)(Sb + 4 * 65536);          // 4 x [256,256] f32
    float*  rs  = Sd + 4 * 65536;                    // [4][256]
    int*    cnt = (int*)(rs + 4 * 256);
    int*    fil = cnt + 4 * 256;
    int*    rowp = fil + 4 * 256;
    const int nnzp = (nnz + 63) & ~63;
    int*    ccol = rowp + 4 * 256;
    float*  cval = (float*)(ccol + 4 * nnzp);

    Graphs G;
    for (int i = 0; i < 4; ++i) {
        G.rows[i] = g_rows[i]; G.cols[i] = g_cols[i]; G.vals[i] = g_vals[i];
        G.cnt[i] = cnt + i * 256; G.fill[i] = fil + i * 256; G.rowptr[i] = rowp + i * 256;
        G.csr_col[i] = ccol + i * nnzp; G.csr_val[i] = cval + i * nnzp;
    }

    // CSR (graphs 0,2 used by scalar kernels; all built cheaply) + dense S
    zero_k<<<(2 * 4 * 256 + 255) / 256, 256, 0, stream>>>(cnt, 2 * 4 * 256);
    zero_k<<<(4 * 65536 + 255) / 256, 256, 0, stream>>>((int*)Sd, 4 * 65536);
    count_k<<<dim3((nnz + 255) / 256, 4), 256, 0, stream>>>(G, nnz);
    scatter_s_k<<<dim3((nnz + 255) / 256, 4), 256, 0, stream>>>(G, Sd, nnz);
    scan_k<<<1, 64, 0, stream>>>(G);
    fill_k<<<dim3((nnz + 255) / 256, 4), 256, 0, stream>>>(G, nnz);
    rowsum_k<<<4, 256, 0, stream>>>(G, rs);
    sconv_k<<<(4 * 65536 + 255) / 256, 256, 0, stream>>>(Sd, Sb, 4 * 65536);

    wconv_k<<<(384 * 416 + 255) / 256, 256, 0, stream>>>(W1, Wt1, 400, 300, 416, 384);
    wconv_k<<<(128 * 320 + 255) / 256, 256, 0, stream>>>(W2, Wt2, 300, 100, 320, 128);
    wconv_k<<<(384 * 128 + 255) / 256, 256, 0, stream>>>(Wd0, Wt3, 100, 300, 128, 384);
    wconv_k<<<(512 * 320 + 255) / 256, 256, 0, stream>>>(Wd1, Wt4, 300, 400, 320, 512);

    const int nrtD = Mp / 128;       // 512 (divisible by 8)
    float* tmpF = (float*)bufT;

    // L0: [2->400] g0, commuted.  H -> tmpF[M,2] -> bufN[Mp,416]
    spmm_f2_f32<<<(M + 255) / 256, 256, 0, stream>>>(H, tmpF, G.rowptr[0], G.csr_col[0], G.csr_val[0], M);
    gemm_k2_relu<<<(Mp * 208 + 255) / 256, 256, 0, stream>>>(tmpF, W0, b0, rs + 0, bufN, Mp, 400, 416);

    // L1: [400->300] g0.  bufN(K416) -> bufT[B*320,256] -> bufN[,320]
    dense_mfma_T<<<3 * nrtD, 256, 0, stream>>>(Wt1, bufN, b1, bufT, 416, 300, 320, 3, nrtD);
    spmm_mfma_N<<<2 * (B * 320 / 128), 256, 0, stream>>>(Sb + 0 * 65536, bufT, bufN, 320, B * 320 / 128);

    // L2: [300->100] g1.  bufN(K320) -> bufT[B*128,256] -> bufN[,128]
    dense_mfma_T<<<1 * nrtD, 256, 0, stream>>>(Wt2, bufN, b2, bufT, 320, 100, 128, 1, nrtD);
    spmm_mfma_N<<<2 * (B * 128 / 128), 256, 0, stream>>>(Sb + 1 * 65536, bufT, bufN, 128, B * 128 / 128);

    // L3: [100->300] g3.  bufN(K128) -> bufT[B*320,256] -> bufN[,320]
    dense_mfma_T<<<3 * nrtD, 256, 0, stream>>>(Wt3, bufN, bd0, bufT, 128, 300, 320, 3, nrtD);
    spmm_mfma_N<<<2 * (B * 320 / 128), 256, 0, stream>>>(Sb + 3 * 65536, bufT, bufN, 320, B * 320 / 128);

    // L4: [300->400] g2.  bufN(K320) -> bufT[B*400,256] -> bufN[,400]
    dense_mfma_T<<<4 * nrtD, 256, 0, stream>>>(Wt4, bufN, bd1, bufT, 320, 400, 400, 4, nrtD);
    spmm_mfma_N<<<2 * (B * 400 / 128), 256, 0, stream>>>(Sb + 2 * 65536, bufT, bufN, 400, B * 400 / 128);

    // L5: [400->2] g2.  bufN[Mp,400] -> tmpF[Mp,2] -> out[M,2]
    gemm_n2_bf16<<<(Mp * 64 + 255) / 256, 256, 0, stream>>>(bufN, Wd2, bd2, tmpF, Mp, 400);
    spmm_final_k<<<(M + 255) / 256, 256, 0, stream>>>(tmpF, out, G.rowptr[2], G.csr_col[2], G.csr_val[2], M);
}